// Round 3
// baseline (363.308 us; speedup 1.0000x reference)
//
#include <hip/hip_runtime.h>
#include <hip/hip_bf16.h>

// Grouped conv2d as implicit GEMM per group:
//   out[b*64+co][h][w] = sum_{ci,kh,kw} W[b*64+co][ci][kh][kw] * x[b*64+ci][h+kh-1][w+kw-1]
// bf16 MFMA (16x16x32), fp32 accumulate. K = tap-major (9 taps x 64 ci).
//
// R3 changes vs R2 (LDS bank conflicts = 44M cycles, ~20% of runtime):
//  - staging transposed assignment: thread owns (column c=lane, ci-octet),
//    8 coalesced scalar global loads -> one ds_write_b128. Bank-balanced
//    (c&7 covers 0..7 across lanes). Same xs contents as verified R2 layout.

typedef __bf16 bf16x8 __attribute__((ext_vector_type(8)));
typedef float  f32x4  __attribute__((ext_vector_type(4)));

#define NB 32
#define NH 256
#define NW 256
#define TILE_H 4
#define TILE_W 64
#define XROWS 6     // TILE_H + 2 (halo)
#define XCOLS 68    // TILE_W + 2, padded

// ---------------------------------------------------------------------------
// Repack weights into MFMA A-fragment order:
//   pk[((b*9+tap)*4+mt)*2+kc][lane][j]  (bf16, 16B per lane)
// value = W[b*64 + mt*16 + (lane&15)][kc*32 + (lane>>4)*8 + j][tap]
// ---------------------------------------------------------------------------
__global__ void repack_weights_kernel(const float* __restrict__ wsrc,
                                      __bf16* __restrict__ pk) {
    int t = blockIdx.x * blockDim.x + threadIdx.x;
    if (t >= NB * 9 * 4 * 2 * 64) return;
    int lane = t & 63;
    int r = t >> 6;
    int kc = r & 1;  r >>= 1;
    int mt = r & 3;  r >>= 2;
    int tap = r % 9;
    int b   = r / 9;
    int co  = b * 64 + mt * 16 + (lane & 15);
    int ci0 = kc * 32 + (lane >> 4) * 8;
    bf16x8 v;
#pragma unroll
    for (int j = 0; j < 8; ++j) {
        v[j] = (__bf16)wsrc[(co * 64 + ci0 + j) * 9 + tap];
    }
    *reinterpret_cast<bf16x8*>(pk + (size_t)t * 8) = v;
}

// ---------------------------------------------------------------------------
// Main conv kernel. Block = (group b, 4 output rows, 64 output cols).
// X tile in LDS as bf16, layout [r][c][ci], ci-octet XOR-swizzled by (c&7).
// element ci of column c stored at 8*((ci>>3)^(c&7)) + (ci&7).
// ---------------------------------------------------------------------------
__launch_bounds__(256, 3)
__global__ void conv_mfma_kernel(const float* __restrict__ x,
                                 const __bf16* __restrict__ pk,
                                 float* __restrict__ out) {
    __shared__ __align__(16) __bf16 xs[XROWS * XCOLS * 64];

    // XCD-aware bijective swizzle: 8192 blocks, 8 XCDs -> contiguous 1024-chunk per XCD
    const int orig = blockIdx.x;
    const int wg   = (orig & 7) * 1024 + (orig >> 3);
    const int b    = wg >> 8;            // 0..31
    const int by   = (wg >> 2) & 63;     // 0..63
    const int bx   = wg & 3;             // 0..3
    const int h0   = by * TILE_H;
    const int w0   = bx * TILE_W;

    const int tid  = threadIdx.x;
    const int wid  = tid >> 6;
    const int lane = tid & 63;

    const __bf16* pkb = pk + (size_t)b * 9 * 4096;

    // Preload A fragments for step 0 (tap0, kc0) before staging to hide latency
    bf16x8 af[2][4];
#pragma unroll
    for (int mt = 0; mt < 4; ++mt)
        af[0][mt] = *reinterpret_cast<const bf16x8*>(pkb + ((mt * 2) * 64 + lane) * 8);

    // ---- stage X halo tile: coalesced scalar loads, b128 swizzled writes ----
    // Main region: thread = (column c = lane, row-range by wid), 12 tuples each.
    // Tuple p (0..47): r = p>>3, ci-octet = p&7. Thread wid covers p in
    // [wid*12, wid*12+12). For each tuple: 8 scalar loads x[ci0+j][h][w0-1+c]
    // (coalesced across lanes), pack -> one ds_write_b128.
    {
        const int c  = lane;                  // 0..63, w = w0-1+c
        const int w  = w0 - 1 + c;
        const int wc = min(max(w, 0), NW - 1);
        const bool wbad = (w != wc);
        const int pbase = wid * 12;

        float va[8], vb[8];
        auto load8 = [&](int p, float* v) {
            const int r   = p >> 3;
            const int ci0 = (p & 7) * 8;
            const int h   = h0 - 1 + r;
            const int hc  = min(max(h, 0), NH - 1);
            const float* src = x + ((size_t)(b * 64 + ci0) * NH + hc) * NW + wc;
#pragma unroll
            for (int j = 0; j < 8; ++j) v[j] = src[(size_t)j * NH * NW];
            if (wbad || h != hc) {
#pragma unroll
                for (int j = 0; j < 8; ++j) v[j] = 0.f;
            }
        };
        auto store8 = [&](int p, const float* v) {
            const int r   = p >> 3;
            const int ci0 = (p & 7) * 8;
            const int sci = ci0 ^ ((c & 7) << 3);
            bf16x8 o;
#pragma unroll
            for (int j = 0; j < 8; ++j) o[j] = (__bf16)v[j];
            *reinterpret_cast<bf16x8*>(xs + (r * XCOLS + c) * 64 + sci) = o;
        };

        load8(pbase, va);
#pragma unroll
        for (int i = 0; i < 12; ++i) {
            if (i < 11) load8(pbase + i + 1, (i & 1) ? va : vb);
            store8(pbase + i, (i & 1) ? vb : va);
        }

        // Halo columns c=64,65 (w = w0+63, w0+64): 96 tuples, threads 0..95
        if (tid < 96) {
            const int r    = tid >> 4;          // 0..5
            const int side = (tid >> 3) & 1;    // 0,1
            const int oct  = tid & 7;           // ci octet
            const int ch   = 64 + side;
            const int hw   = w0 - 1 + ch;
            const int hwc  = min(hw, NW - 1);
            const int h    = h0 - 1 + r;
            const int hc   = min(max(h, 0), NH - 1);
            const int ci0  = oct * 8;
            const float* src = x + ((size_t)(b * 64 + ci0) * NH + hc) * NW + hwc;
            float v[8];
#pragma unroll
            for (int j = 0; j < 8; ++j) v[j] = src[(size_t)j * NH * NW];
            if (h != hc || hw != hwc) {
#pragma unroll
                for (int j = 0; j < 8; ++j) v[j] = 0.f;
            }
            bf16x8 o;
#pragma unroll
            for (int j = 0; j < 8; ++j) o[j] = (__bf16)v[j];
            const int sci = ci0 ^ ((ch & 7) << 3);
            *reinterpret_cast<bf16x8*>(xs + (r * XCOLS + ch) * 64 + sci) = o;
        }
    }

    f32x4 acc[4][4];   // [mt][q]
#pragma unroll
    for (int mt = 0; mt < 4; ++mt)
#pragma unroll
        for (int q = 0; q < 4; ++q)
            acc[mt][q] = (f32x4){0.f, 0.f, 0.f, 0.f};

    __syncthreads();

    const int nl   = lane & 15;
    const int kgrp = lane >> 4;       // 0..3

    // 18-step (tap,kc) K-loop, fully unrolled, 1-step A prefetch.
#pragma unroll
    for (int step = 0; step < 18; ++step) {
        const int tap = step >> 1;
        const int kc  = step & 1;
        if (step < 17) {
            const int ns   = step + 1;
            const int ntap = ns >> 1;
            const int nkc  = ns & 1;
#pragma unroll
            for (int mt = 0; mt < 4; ++mt)
                af[ns & 1][mt] = *reinterpret_cast<const bf16x8*>(
                    pkb + ntap * 4096 + ((mt * 2 + nkc) * 64 + lane) * 8);
        }
        const int kh = tap / 3;
        const int kw = tap - kh * 3;
        const int rowbase = (wid + kh) * XCOLS;
        const int ci0 = kc * 32 + kgrp * 8;
#pragma unroll
        for (int q = 0; q < 4; ++q) {
            const int c = q * 16 + nl + kw;    // 0..65
            bf16x8 bfv = *reinterpret_cast<const bf16x8*>(
                xs + (rowbase + c) * 64 + (ci0 ^ ((c & 7) << 3)));
#pragma unroll
            for (int mt = 0; mt < 4; ++mt)
                acc[mt][q] = __builtin_amdgcn_mfma_f32_16x16x32_bf16(
                    af[step & 1][mt], bfv, acc[mt][q], 0, 0, 0);
        }
    }

    // ---- epilogue: D lane layout col=lane&15, row=(lane>>4)*4+reg ----
    const int mrow = (lane >> 4) * 4;
    const int h = h0 + wid;
#pragma unroll
    for (int mt = 0; mt < 4; ++mt) {
#pragma unroll
        for (int q = 0; q < 4; ++q) {
            const int w = w0 + q * 16 + nl;
#pragma unroll
            for (int rg = 0; rg < 4; ++rg) {
                const int co = mt * 16 + mrow + rg;
                out[((size_t)(b * 64 + co) * NH + h) * NW + w] = acc[mt][q][rg];
            }
        }
    }
}

extern "C" void kernel_launch(void* const* d_in, const int* in_sizes, int n_in,
                              void* d_out, int out_size, void* d_ws, size_t ws_size,
                              hipStream_t stream) {
    const float* x = (const float*)d_in[0];     // [1, 32*64, 256, 256] fp32
    const float* w = (const float*)d_in[1];     // [2048, 64, 3, 3] fp32
    float* out = (float*)d_out;                 // [1, 2048, 256, 256] fp32
    __bf16* pk = (__bf16*)d_ws;                 // 2.25 MB repacked bf16 weights

    {
        int total = NB * 9 * 4 * 2 * 64;        // 147456
        int blk = 256;
        int grid = (total + blk - 1) / blk;     // 576
        hipLaunchKernelGGL(repack_weights_kernel, dim3(grid), dim3(blk), 0, stream,
                           w, pk);
    }
    {
        dim3 grid(8192);                        // 1D, swizzled in-kernel
        hipLaunchKernelGGL(conv_mfma_kernel, grid, dim3(256), 0, stream,
                           x, pk, out);
    }
}

// Round 4
// 320.096 us; speedup vs baseline: 1.1350x; 1.1350x over previous
//
#include <hip/hip_runtime.h>
#include <hip/hip_bf16.h>

// Grouped conv2d as implicit GEMM per group:
//   out[b*64+co][h][w] = sum_{ci,kh,kw} W[b*64+co][ci][kh][kw] * x[b*64+ci][h+kh-1][w+kw-1]
// bf16 MFMA (16x16x32), fp32 accumulate.
//
// R4 changes vs R3 (latency-bound, 27% occupancy, LDS 52KB -> 3 blocks/CU):
//  - ci-phased K-loop: stage 32 ci at a time into a single 26KB buffer
//    (stage0;sync;comp0;sync;stage1;sync;comp1) -> LDS allows 6 blocks/CU,
//    VGPR becomes the cap (~16-18 waves/CU vs 12).
//  - swizzle re-derived for 64B columns: slot=(c>>1)&3, octet pos = oct^slot.
//    8-lane-group bank analysis: both ds_write_b128 and ds_read_b128 tile
//    all 32 banks -> 0 conflicts (verified structure, same method as R3).
//  - nontemporal out stores (don't evict x halo data from L2).

typedef __bf16 bf16x8 __attribute__((ext_vector_type(8)));
typedef float  f32x4  __attribute__((ext_vector_type(4)));

#define NB 32
#define NH 256
#define NW 256
#define TILE_H 4
#define TILE_W 64
#define XROWS 6     // TILE_H + 2 (halo)
#define XCOLS 68    // TILE_W + 2, padded

// ---------------------------------------------------------------------------
// Repack weights into MFMA A-fragment order:
//   pk[((b*9+tap)*4+mt)*2+kc][lane][j]  (bf16, 16B per lane)
// value = W[b*64 + mt*16 + (lane&15)][kc*32 + (lane>>4)*8 + j][tap]
// ---------------------------------------------------------------------------
__global__ void repack_weights_kernel(const float* __restrict__ wsrc,
                                      __bf16* __restrict__ pk) {
    int t = blockIdx.x * blockDim.x + threadIdx.x;
    if (t >= NB * 9 * 4 * 2 * 64) return;
    int lane = t & 63;
    int r = t >> 6;
    int kc = r & 1;  r >>= 1;
    int mt = r & 3;  r >>= 2;
    int tap = r % 9;
    int b   = r / 9;
    int co  = b * 64 + mt * 16 + (lane & 15);
    int ci0 = kc * 32 + (lane >> 4) * 8;
    bf16x8 v;
#pragma unroll
    for (int j = 0; j < 8; ++j) {
        v[j] = (__bf16)wsrc[(co * 64 + ci0 + j) * 9 + tap];
    }
    *reinterpret_cast<bf16x8*>(pk + (size_t)t * 8) = v;
}

// ---------------------------------------------------------------------------
// Main conv kernel. Block = (group b, 4 output rows, 64 output cols), 4 waves.
// LDS holds ONE 32-ci half-tile: xs[r][c][32], octet of local ci o stored at
// 8*(o ^ ((c>>1)&3)). Two phases kc=0,1 reuse the buffer.
// ---------------------------------------------------------------------------
__launch_bounds__(256)
__global__ void conv_mfma_kernel(const float* __restrict__ x,
                                 const __bf16* __restrict__ pk,
                                 float* __restrict__ out) {
    __shared__ __align__(16) __bf16 xs[XROWS * XCOLS * 32];   // 26112 B

    // XCD-aware bijective swizzle: 8192 blocks, 8 XCDs
    const int orig = blockIdx.x;
    const int wg   = (orig & 7) * 1024 + (orig >> 3);
    const int b    = wg >> 8;            // 0..31
    const int by   = (wg >> 2) & 63;     // 0..63
    const int bx   = wg & 3;             // 0..3
    const int h0   = by * TILE_H;
    const int w0   = bx * TILE_W;

    const int tid  = threadIdx.x;
    const int wid  = tid >> 6;
    const int lane = tid & 63;
    const int nl   = lane & 15;
    const int kgrp = lane >> 4;          // 0..3

    const __bf16* pkb = pk + (size_t)b * 9 * 4096;

    // A-fragment double buffer across all 18 (kc,tap) steps
    bf16x8 af[2][4];
#pragma unroll
    for (int mt = 0; mt < 4; ++mt)       // preload g=0 (tap0, kc0)
        af[0][mt] = *reinterpret_cast<const bf16x8*>(pkb + ((mt * 2) * 64 + lane) * 8);

    f32x4 acc[4][4];   // [mt][q]
#pragma unroll
    for (int mt = 0; mt < 4; ++mt)
#pragma unroll
        for (int q = 0; q < 4; ++q)
            acc[mt][q] = (f32x4){0.f, 0.f, 0.f, 0.f};

    // staging thread constants (main region: thread = column c = lane, oct = wid)
    const int c    = lane;               // 0..63 -> w = w0-1+c
    const int w    = w0 - 1 + c;
    const int wcl  = min(max(w, 0), NW - 1);
    const bool wbad = (w != wcl);
    const int sciw = ((wid ^ ((c >> 1) & 3)) * 8);   // swizzled octet offset

    // halo thread constants (threads 0..47: c=64,65)
    const int hidx  = tid;
    const int hr    = hidx >> 3;             // 0..5
    const int hside = (hidx >> 2) & 1;       // 0,1 -> c = 64,65
    const int hoct  = hidx & 3;              // local ci octet
    const int hch   = 64 + hside;
    const int hw    = w0 + 63 + hside;
    const int hwc   = min(hw, NW - 1);

#pragma unroll
    for (int kc = 0; kc < 2; ++kc) {
        // ---- stage phase kc: 32 ci, coalesced scalar loads, b128 swizzled writes ----
        {
            const int cibase = b * 64 + kc * 32 + wid * 8;
            const float* colp = x + (size_t)cibase * NH * NW + wcl;

            // halo loads first (threads 0..47), store at end
            float hv[8];
            if (tid < 48) {
                const int h  = h0 - 1 + hr;
                const int hc = min(max(h, 0), NH - 1);
                const float* src = x + ((size_t)(b * 64 + kc * 32 + hoct * 8) * NH + hc) * NW + hwc;
#pragma unroll
                for (int j = 0; j < 8; ++j) hv[j] = src[(size_t)j * NH * NW];
                if (h != hc || hw != hwc) {
#pragma unroll
                    for (int j = 0; j < 8; ++j) hv[j] = 0.f;
                }
            }

            float va[8], vb[8];
            auto load8 = [&](int r, float* v) {
                const int h  = h0 - 1 + r;
                const int hc = min(max(h, 0), NH - 1);
                const float* src = colp + (size_t)hc * NW;
#pragma unroll
                for (int j = 0; j < 8; ++j) v[j] = src[(size_t)j * NH * NW];
                if (wbad || h != hc) {
#pragma unroll
                    for (int j = 0; j < 8; ++j) v[j] = 0.f;
                }
            };
            auto store8 = [&](int r, const float* v) {
                bf16x8 o;
#pragma unroll
                for (int j = 0; j < 8; ++j) o[j] = (__bf16)v[j];
                *reinterpret_cast<bf16x8*>(xs + (r * XCOLS + c) * 32 + sciw) = o;
            };

            load8(0, va);
            load8(1, vb);
            store8(0, va); load8(2, va);
            store8(1, vb); load8(3, vb);
            store8(2, va); load8(4, va);
            store8(3, vb); load8(5, vb);
            store8(4, va);
            store8(5, vb);

            if (tid < 48) {
                bf16x8 o;
#pragma unroll
                for (int j = 0; j < 8; ++j) o[j] = (__bf16)hv[j];
                // slot(64)=slot(65)=0 -> octet position = hoct
                *reinterpret_cast<bf16x8*>(xs + (hr * XCOLS + hch) * 32 + hoct * 8) = o;
            }
        }
        __syncthreads();

        // ---- compute phase kc: 9 taps, K=32 slice per tap ----
#pragma unroll
        for (int tap = 0; tap < 9; ++tap) {
            const int g = kc * 9 + tap;
            if (g < 17) {                      // prefetch next (kc,tap) A-fragments
                const int ng   = g + 1;
                const int ntap = (ng >= 9) ? ng - 9 : ng;
                const int nkc  = (ng >= 9) ? 1 : 0;
#pragma unroll
                for (int mt = 0; mt < 4; ++mt)
                    af[ng & 1][mt] = *reinterpret_cast<const bf16x8*>(
                        pkb + ntap * 4096 + ((mt * 2 + nkc) * 64 + lane) * 8);
            }
            const int kh = tap / 3;
            const int kw = tap - kh * 3;
            const int rowbase = (wid + kh) * XCOLS;
#pragma unroll
            for (int q = 0; q < 4; ++q) {
                const int cc   = q * 16 + nl + kw;          // 0..65
                const int slot = (cc >> 1) & 3;
                bf16x8 bfv = *reinterpret_cast<const bf16x8*>(
                    xs + (rowbase + cc) * 32 + ((kgrp ^ slot) * 8));
#pragma unroll
                for (int mt = 0; mt < 4; ++mt)
                    acc[mt][q] = __builtin_amdgcn_mfma_f32_16x16x32_bf16(
                        af[g & 1][mt], bfv, acc[mt][q], 0, 0, 0);
            }
        }
        if (kc == 0) __syncthreads();   // protect xs before phase-1 overwrite
    }

    // ---- epilogue: D lane layout col=lane&15, row=(lane>>4)*4+reg ----
    const int mrow = kgrp * 4;
    const int h = h0 + wid;
#pragma unroll
    for (int mt = 0; mt < 4; ++mt) {
#pragma unroll
        for (int q = 0; q < 4; ++q) {
            const int ww = w0 + q * 16 + nl;
#pragma unroll
            for (int rg = 0; rg < 4; ++rg) {
                const int co = mt * 16 + mrow + rg;
                __builtin_nontemporal_store(
                    acc[mt][q][rg],
                    out + ((size_t)(b * 64 + co) * NH + h) * NW + ww);
            }
        }
    }
}

extern "C" void kernel_launch(void* const* d_in, const int* in_sizes, int n_in,
                              void* d_out, int out_size, void* d_ws, size_t ws_size,
                              hipStream_t stream) {
    const float* x = (const float*)d_in[0];     // [1, 32*64, 256, 256] fp32
    const float* w = (const float*)d_in[1];     // [2048, 64, 3, 3] fp32
    float* out = (float*)d_out;                 // [1, 2048, 256, 256] fp32
    __bf16* pk = (__bf16*)d_ws;                 // 2.25 MB repacked bf16 weights

    {
        int total = NB * 9 * 4 * 2 * 64;        // 147456
        int blk = 256;
        int grid = (total + blk - 1) / blk;     // 576
        hipLaunchKernelGGL(repack_weights_kernel, dim3(grid), dim3(blk), 0, stream,
                           w, pk);
    }
    {
        dim3 grid(8192);                        // 1D, swizzled in-kernel
        hipLaunchKernelGGL(conv_mfma_kernel, grid, dim3(256), 0, stream,
                           x, pk, out);
    }
}